// Round 8
// baseline (46.659 us; speedup 1.0000x reference)
//
#include <hip/hip_runtime.h>

#define BATCH 8192
#define DIM 128
#define NREL 1000
#define MARGIN 1.0f
#define GRID 2800        // = 350*8 -> bijective XCD swizzle; 1 block per group
#define ORDER_CAP 11200  // GRID*4 >= max padded total (8192 + 3*1000 = 11192)

// ws layout (4 B units): partial[8192] | cnt[1024] | order[11200]
#define WS_PARTIAL 0
#define WS_CNT 8192
#define WS_ORDER 9216

// 32-block histogram over relations (device-scope atomics, ~8/bin contention)
__global__ __launch_bounds__(256) void hist_kernel(const int* __restrict__ r_idx,
                                                   int* __restrict__ cnt) {
  const int i = blockIdx.x * 256 + threadIdx.x;  // grid covers BATCH exactly
  atomicAdd(&cnt[r_idx[i]], 1);
}

// Single-block in-place exclusive scan of pad4 counts -> cursor (reuses cnt).
// Each thread owns 4 disjoint bins: read own, scan via shfl, write own. Safe.
__global__ __launch_bounds__(256) void scan_kernel(int* __restrict__ cnt) {
  const int tid = threadIdx.x, lane = tid & 63, wave = tid >> 6;
  const int base = tid * 4;
  int c[4], lsum = 0;
#pragma unroll
  for (int k = 0; k < 4; ++k) {
    const int i = base + k;
    c[k] = (i < NREL) ? ((cnt[i] + 3) & ~3) : 0;  // pad runs to multiple of 4
    lsum += c[k];
  }
  int v = lsum;
#pragma unroll
  for (int o = 1; o < 64; o <<= 1) {
    int u = __shfl_up(v, o, 64);
    if (lane >= o) v += u;
  }
  __shared__ int wsum[4];
  if (lane == 63) wsum[wave] = v;
  __syncthreads();
  int woff = 0;
  for (int w = 0; w < wave; ++w) woff += wsum[w];
  int toff = woff + v - lsum;
#pragma unroll
  for (int k = 0; k < 4; ++k) {
    cnt[base + k] = toff;  // cursor
    toff += c[k];
  }
}

__global__ __launch_bounds__(256) void scatter_kernel(const int* __restrict__ r_idx,
                                                      int* __restrict__ cursor,
                                                      int* __restrict__ order) {
  const int i = blockIdx.x * 256 + threadIdx.x;
  const int p = atomicAdd(&cursor[r_idx[i]], 1);
  order[p] = i;
}

__device__ inline float2 dvec(const float* __restrict__ b, int c0) {
  float2 h = *(const float2*)(b + c0);
  float2 r = *(const float2*)(b + DIM + c0);
  float2 t = *(const float2*)(b + 2 * DIM + c0);
  return make_float2(fabsf(h.x + r.x - t.x), fabsf(h.y + r.y - t.y));
}

// One block per 4-element same-relation group; wave w covers W rows
// [32w, 32w+32). d staged ONCE (wave 0) in conflict-free lane-major
// stride-20 layout; all 4 waves read 2-address broadcasts from it.
// Epilogue d from registers via __shfl (every wave loads d regs; L1-hot).
// Per-wave partial s combined across waves via tiny LDS.
__global__ __launch_bounds__(256) void score_kernel(
    const float* __restrict__ pos_b, const float* __restrict__ neg_b,
    const int* __restrict__ r_idx, const float* __restrict__ rel_emb,
    const int* __restrict__ order, float* __restrict__ partial) {
  __shared__ float s_d[64 * 20];  // 5 KB, shared by all waves
  __shared__ float s_ps[4][4];
  const int tid = threadIdx.x, lane = tid & 63, wave = tid >> 6;
  // bijective XCD swizzle: each XCD gets a contiguous run of sorted groups
  const int phys = blockIdx.x;
  const int g = (phys & 7) * (GRID / 8) + (phys >> 3);
  int4 es = *(const int4*)(order + g * 4);
  if (es.x < 0) return;  // block-uniform exit (no barrier reached by anyone)

  const int c0 = lane * 2;
  const int r = r_idx[es.x];
  const bool v1 = es.y >= 0, v2 = es.z >= 0, v3 = es.w >= 0;
  const int e1 = v1 ? es.y : es.x, e2 = v2 ? es.z : es.x, e3 = v3 ? es.w : es.x;

  const float2 z = make_float2(0.f, 0.f);
  float2 dp0 = dvec(pos_b + (size_t)es.x * 3 * DIM, c0);
  float2 dn0 = dvec(neg_b + (size_t)es.x * 3 * DIM, c0);
  float2 dp1 = v1 ? dvec(pos_b + (size_t)e1 * 3 * DIM, c0) : z;
  float2 dn1 = v1 ? dvec(neg_b + (size_t)e1 * 3 * DIM, c0) : z;
  float2 dp2 = v2 ? dvec(pos_b + (size_t)e2 * 3 * DIM, c0) : z;
  float2 dn2 = v2 ? dvec(neg_b + (size_t)e2 * 3 * DIM, c0) : z;
  float2 dp3 = v3 ? dvec(pos_b + (size_t)e3 * 3 * DIM, c0) : z;
  float2 dn3 = v3 ? dvec(neg_b + (size_t)e3 * 3 * DIM, c0) : z;

  if (wave == 0) {
    // lane l stages unit l (rows 2l,2l+1) at l*20 floats; quad start
    // (20l)%32 sweeps all 8 bank-quads across l&7 -> conflict-free writes.
    float* myd = &s_d[lane * 20];
    *(float4*)(myd + 0)  = make_float4(dp0.x, dp1.x, dp2.x, dp3.x);
    *(float4*)(myd + 4)  = make_float4(dn0.x, dn1.x, dn2.x, dn3.x);
    *(float4*)(myd + 8)  = make_float4(dp0.y, dp1.y, dp2.y, dp3.y);
    *(float4*)(myd + 12) = make_float4(dn0.y, dn1.y, dn2.y, dn3.y);
  }
  __syncthreads();

  const int colb = (lane & 31) * 4;
  const int rsel = lane >> 5;
  const float* W = rel_emb + (size_t)r * (DIM * DIM) +
                   (size_t)(wave * 32 + rsel) * DIM + colb;
  // unit u = 16*wave + it; dp at u*20 (+8 if odd row), dn at +4
  const float* dptr = s_d + (wave * 16) * 20 + rsel * 8;

  const float4 fz = make_float4(0.f, 0.f, 0.f, 0.f);
  float4 ap0 = fz, ap1 = fz, ap2 = fz, ap3 = fz;
  float4 an0 = fz, an1 = fz, an2 = fz, an3 = fz;

#define FMA4(ACC, D, WV)          \
  ACC.x = fmaf(D, WV.x, ACC.x);   \
  ACC.y = fmaf(D, WV.y, ACC.y);   \
  ACC.z = fmaf(D, WV.z, ACC.z);   \
  ACC.w = fmaf(D, WV.w, ACC.w);

#pragma unroll 8
  for (int it = 0; it < 16; ++it) {
    float4 wv = *(const float4*)(W + (size_t)(it * 2) * DIM);
    float4 ddp = *(const float4*)(dptr + it * 20);      // 2-addr broadcast
    float4 ddn = *(const float4*)(dptr + it * 20 + 4);  // 2-addr broadcast
    FMA4(ap0, ddp.x, wv) FMA4(ap1, ddp.y, wv)
    FMA4(ap2, ddp.z, wv) FMA4(ap3, ddp.w, wv)
    FMA4(an0, ddn.x, wv) FMA4(an1, ddn.y, wv)
    FMA4(an2, ddn.z, wv) FMA4(an3, ddn.w, wv)
  }
#undef FMA4

  // epilogue: lane lam owns cols 4lam..4lam+3; d for those cols lives in
  // lanes 2lam, 2lam+1 registers -> __shfl. Lanes l and l+32 hold different
  // row-subsets of the same cols; the 64-lane reduce sums them.
  const int sl0 = (lane & 31) * 2, sl1 = sl0 + 1;
#define GET4(OUT0, OUT1, OUT2, OUT3, V)   \
  OUT0 = __shfl(V.x, sl0, 64);            \
  OUT1 = __shfl(V.y, sl0, 64);            \
  OUT2 = __shfl(V.x, sl1, 64);            \
  OUT3 = __shfl(V.y, sl1, 64);
  float a, b, c, d, e, f, gg, h;
  float s0, s1, s2, s3;
  GET4(a, b, c, d, dp0) GET4(e, f, gg, h, dn0)
  s0 = ap0.x * a + ap0.y * b + ap0.z * c + ap0.w * d -
       (an0.x * e + an0.y * f + an0.z * gg + an0.w * h);
  GET4(a, b, c, d, dp1) GET4(e, f, gg, h, dn1)
  s1 = ap1.x * a + ap1.y * b + ap1.z * c + ap1.w * d -
       (an1.x * e + an1.y * f + an1.z * gg + an1.w * h);
  GET4(a, b, c, d, dp2) GET4(e, f, gg, h, dn2)
  s2 = ap2.x * a + ap2.y * b + ap2.z * c + ap2.w * d -
       (an2.x * e + an2.y * f + an2.z * gg + an2.w * h);
  GET4(a, b, c, d, dp3) GET4(e, f, gg, h, dn3)
  s3 = ap3.x * a + ap3.y * b + ap3.z * c + ap3.w * d -
       (an3.x * e + an3.y * f + an3.z * gg + an3.w * h);
#undef GET4

#pragma unroll
  for (int o = 32; o > 0; o >>= 1) {
    s0 += __shfl_xor(s0, o, 64);
    s1 += __shfl_xor(s1, o, 64);
    s2 += __shfl_xor(s2, o, 64);
    s3 += __shfl_xor(s3, o, 64);
  }
  if (lane == 0) {
    s_ps[wave][0] = s0; s_ps[wave][1] = s1;
    s_ps[wave][2] = s2; s_ps[wave][3] = s3;
  }
  __syncthreads();
  if (tid == 0) {
    float t0 = s_ps[0][0] + s_ps[1][0] + s_ps[2][0] + s_ps[3][0];
    float t1 = s_ps[0][1] + s_ps[1][1] + s_ps[2][1] + s_ps[3][1];
    float t2 = s_ps[0][2] + s_ps[1][2] + s_ps[2][2] + s_ps[3][2];
    float t3 = s_ps[0][3] + s_ps[1][3] + s_ps[2][3] + s_ps[3][3];
    partial[es.x] = t0;
    if (v1) partial[es.y] = t1;
    if (v2) partial[es.z] = t2;
    if (v3) partial[es.w] = t3;
  }
}

__global__ __launch_bounds__(1024) void reduce_kernel(const float* __restrict__ partial,
                                                      float* __restrict__ out) {
  float acc = 0.f;
  for (int i = threadIdx.x; i < BATCH; i += 1024) {
    float v = MARGIN + partial[i];
    acc += (v > 0.f) ? v : 0.f;
  }
#pragma unroll
  for (int o = 32; o > 0; o >>= 1) acc += __shfl_xor(acc, o, 64);
  __shared__ float s[16];
  const int lane = threadIdx.x & 63, wave = threadIdx.x >> 6;
  if (lane == 0) s[wave] = acc;
  __syncthreads();
  if (threadIdx.x == 0) {
    float t = 0.f;
    for (int w = 0; w < 16; ++w) t += s[w];
    out[0] = t * (1.0f / BATCH);
  }
}

extern "C" void kernel_launch(void* const* d_in, const int* in_sizes, int n_in,
                              void* d_out, int out_size, void* d_ws, size_t ws_size,
                              hipStream_t stream) {
  const float* pos_b = (const float*)d_in[0];
  const float* neg_b = (const float*)d_in[1];
  const int* r_idx = (const int*)d_in[2];
  const float* rel_emb = (const float*)d_in[3];
  float* out = (float*)d_out;

  float* partial = (float*)d_ws + WS_PARTIAL;
  int* cnt = (int*)d_ws + WS_CNT;    // becomes cursor after scan
  int* order = (int*)d_ws + WS_ORDER;

  hipMemsetAsync(cnt, 0, 1024 * sizeof(int), stream);
  hipMemsetAsync(order, 0xFF, ORDER_CAP * sizeof(int), stream);  // -1 fill
  hist_kernel<<<BATCH / 256, 256, 0, stream>>>(r_idx, cnt);
  scan_kernel<<<1, 256, 0, stream>>>(cnt);
  scatter_kernel<<<BATCH / 256, 256, 0, stream>>>(r_idx, cnt, order);
  score_kernel<<<GRID, 256, 0, stream>>>(pos_b, neg_b, r_idx, rel_emb, order,
                                         partial);
  reduce_kernel<<<1, 1024, 0, stream>>>(partial, out);
}

// Round 9
// 45.904 us; speedup vs baseline: 1.0165x; 1.0165x over previous
//
#include <hip/hip_runtime.h>

#define BATCH 8192
#define DIM 128
#define NREL 1000
#define MARGIN 1.0f
#define GRID 1400        // total score blocks (2 groups of 4 elems each)
#define HALF 700         // each A/B kernel takes half the blocks
#define ORDER_CAP 11264  // >= max padded total (8192 + 3*1000 = 11192)

// ws layout (4 B units): pA[8192] | pB[8192] | order[11264]
#define WS_PA 0
#define WS_PB 8192
#define WS_ORDER 16384

// Fused single-block counting sort: zero + count + pad4-scan + init + scatter.
__global__ __launch_bounds__(1024) void sort_kernel(const int* __restrict__ r_idx,
                                                    int* __restrict__ order) {
  __shared__ int s_cnt[1024];
  __shared__ int s_cur[1024];
  __shared__ int s_wsum[16];
  const int tid = threadIdx.x, lane = tid & 63, wave = tid >> 6;
  s_cnt[tid] = 0;
  __syncthreads();
  int my[8];
#pragma unroll
  for (int k = 0; k < 8; ++k) {
    my[k] = r_idx[tid + k * 1024];
    atomicAdd(&s_cnt[my[k]], 1);
  }
  __syncthreads();
  const int c = (s_cnt[tid] + 3) & ~3;  // pad runs to multiple of 4
  int v = c;
#pragma unroll
  for (int o = 1; o < 64; o <<= 1) {
    int u = __shfl_up(v, o, 64);
    if (lane >= o) v += u;
  }
  if (lane == 63) s_wsum[wave] = v;
  __syncthreads();
  int woff = 0;
  for (int w = 0; w < wave; ++w) woff += s_wsum[w];
  s_cur[tid] = woff + v - c;
  for (int i = tid; i < ORDER_CAP; i += 1024) order[i] = -1;
  __syncthreads();
#pragma unroll
  for (int k = 0; k < 8; ++k) {
    int p = atomicAdd(&s_cur[my[k]], 1);
    order[p] = tid + k * 1024;
  }
}

__device__ inline float2 dvec(const float* __restrict__ b, int c0) {
  float2 h = *(const float2*)(b + c0);
  float2 r = *(const float2*)(b + DIM + c0);
  float2 t = *(const float2*)(b + 2 * DIM + c0);
  return make_float2(fabsf(h.x + r.x - t.x), fabsf(h.y + r.y - t.y));
}

// m204 general bijective XCD swizzle for nwg not divisible by 8.
__device__ inline int xcd_swz(int phys, int nwg) {
  const int q = nwg >> 3, r = nwg & 7;
  const int xcd = phys & 7, o = phys >> 3;
  return (xcd < r ? xcd * (q + 1) : r * (q + 1) + (xcd - r) * q) + o;
}

// R7-proven structure: 2 waves per 4-element same-relation group; wave half h
// covers rows [64h, 64h+64). Wave-private LDS d-stage, lane-major stride-20
// (conflict-free writes, broadcast reads); epilogue via __shfl; no barriers.
// SWZ templated for the A/B experiment; lb_base selects the group range.
template <int SWZ>
__global__ __launch_bounds__(256) void score_kernel(
    const float* __restrict__ pos_b, const float* __restrict__ neg_b,
    const int* __restrict__ r_idx, const float* __restrict__ rel_emb,
    const int* __restrict__ order, float* __restrict__ pA,
    float* __restrict__ pB, int nwg, int lb_base) {
  __shared__ float s_d[4][64 * 20];  // 5120 B per wave
  const int tid = threadIdx.x, lane = tid & 63, wave = tid >> 6;
  const int phys = blockIdx.x;
  const int lb = (SWZ ? xcd_swz(phys, nwg) : phys) + lb_base;
  const int pair = wave >> 1, half = wave & 1;
  const int g = lb * 2 + pair;
  int4 es = *(const int4*)(order + g * 4);
  if (es.x < 0) return;  // wave-uniform empty group

  const int c0 = lane * 2;
  const int r = r_idx[es.x];
  const bool v1 = es.y >= 0, v2 = es.z >= 0, v3 = es.w >= 0;
  const int e1 = v1 ? es.y : es.x, e2 = v2 ? es.z : es.x, e3 = v3 ? es.w : es.x;

  const float2 z = make_float2(0.f, 0.f);
  float2 dp0 = dvec(pos_b + (size_t)es.x * 3 * DIM, c0);
  float2 dn0 = dvec(neg_b + (size_t)es.x * 3 * DIM, c0);
  float2 dp1 = v1 ? dvec(pos_b + (size_t)e1 * 3 * DIM, c0) : z;
  float2 dn1 = v1 ? dvec(neg_b + (size_t)e1 * 3 * DIM, c0) : z;
  float2 dp2 = v2 ? dvec(pos_b + (size_t)e2 * 3 * DIM, c0) : z;
  float2 dn2 = v2 ? dvec(neg_b + (size_t)e2 * 3 * DIM, c0) : z;
  float2 dp3 = v3 ? dvec(pos_b + (size_t)e3 * 3 * DIM, c0) : z;
  float2 dn3 = v3 ? dvec(neg_b + (size_t)e3 * 3 * DIM, c0) : z;

  {
    float* myd = &s_d[wave][lane * 20];
    *(float4*)(myd + 0)  = make_float4(dp0.x, dp1.x, dp2.x, dp3.x);
    *(float4*)(myd + 4)  = make_float4(dn0.x, dn1.x, dn2.x, dn3.x);
    *(float4*)(myd + 8)  = make_float4(dp0.y, dp1.y, dp2.y, dp3.y);
    *(float4*)(myd + 12) = make_float4(dn0.y, dn1.y, dn2.y, dn3.y);
  }
  // wave-private LDS: in-wave lgkmcnt ordering suffices, no barrier

  const int colb = (lane & 31) * 4;
  const int rsel = lane >> 5;
  const float* W = rel_emb + (size_t)r * (DIM * DIM) +
                   (size_t)(half * 64 + rsel) * DIM + colb;
  const float* dptr = &s_d[wave][(half * 32) * 20 + rsel * 8];

  const float4 fz = make_float4(0.f, 0.f, 0.f, 0.f);
  float4 ap0 = fz, ap1 = fz, ap2 = fz, ap3 = fz;
  float4 an0 = fz, an1 = fz, an2 = fz, an3 = fz;

#define FMA4(ACC, D, WV)          \
  ACC.x = fmaf(D, WV.x, ACC.x);   \
  ACC.y = fmaf(D, WV.y, ACC.y);   \
  ACC.z = fmaf(D, WV.z, ACC.z);   \
  ACC.w = fmaf(D, WV.w, ACC.w);

#pragma unroll 8
  for (int it = 0; it < 32; ++it) {
    float4 wv = *(const float4*)(W + (size_t)(it * 2) * DIM);
    float4 ddp = *(const float4*)(dptr + it * 20);      // 2-addr broadcast
    float4 ddn = *(const float4*)(dptr + it * 20 + 4);  // 2-addr broadcast
    FMA4(ap0, ddp.x, wv) FMA4(ap1, ddp.y, wv)
    FMA4(ap2, ddp.z, wv) FMA4(ap3, ddp.w, wv)
    FMA4(an0, ddn.x, wv) FMA4(an1, ddn.y, wv)
    FMA4(an2, ddn.z, wv) FMA4(an3, ddn.w, wv)
  }
#undef FMA4

  const int sl0 = (lane & 31) * 2, sl1 = sl0 + 1;
#define GET4(OUT0, OUT1, OUT2, OUT3, V)   \
  OUT0 = __shfl(V.x, sl0, 64);            \
  OUT1 = __shfl(V.y, sl0, 64);            \
  OUT2 = __shfl(V.x, sl1, 64);            \
  OUT3 = __shfl(V.y, sl1, 64);
  float a, b, c, d, e, f, gg, h;
  float s0, s1, s2, s3;
  GET4(a, b, c, d, dp0) GET4(e, f, gg, h, dn0)
  s0 = ap0.x * a + ap0.y * b + ap0.z * c + ap0.w * d -
       (an0.x * e + an0.y * f + an0.z * gg + an0.w * h);
  GET4(a, b, c, d, dp1) GET4(e, f, gg, h, dn1)
  s1 = ap1.x * a + ap1.y * b + ap1.z * c + ap1.w * d -
       (an1.x * e + an1.y * f + an1.z * gg + an1.w * h);
  GET4(a, b, c, d, dp2) GET4(e, f, gg, h, dn2)
  s2 = ap2.x * a + ap2.y * b + ap2.z * c + ap2.w * d -
       (an2.x * e + an2.y * f + an2.z * gg + an2.w * h);
  GET4(a, b, c, d, dp3) GET4(e, f, gg, h, dn3)
  s3 = ap3.x * a + ap3.y * b + ap3.z * c + ap3.w * d -
       (an3.x * e + an3.y * f + an3.z * gg + an3.w * h);
#undef GET4

#pragma unroll
  for (int o = 32; o > 0; o >>= 1) {
    s0 += __shfl_xor(s0, o, 64);
    s1 += __shfl_xor(s1, o, 64);
    s2 += __shfl_xor(s2, o, 64);
    s3 += __shfl_xor(s3, o, 64);
  }
  float* P = half ? pB : pA;
  if (lane == 0) {
    P[es.x] = s0;
    if (v1) P[es.y] = s1;
    if (v2) P[es.z] = s2;
    if (v3) P[es.w] = s3;
  }
}

__global__ __launch_bounds__(256) void reduce_kernel(const float* __restrict__ pA,
                                                     const float* __restrict__ pB,
                                                     float* __restrict__ out) {
  float acc = 0.f;
  for (int i = threadIdx.x; i < BATCH; i += 256) {
    float v = MARGIN + pA[i] + pB[i];
    acc += (v > 0.f) ? v : 0.f;
  }
#pragma unroll
  for (int o = 32; o > 0; o >>= 1) acc += __shfl_xor(acc, o, 64);
  __shared__ float s[4];
  const int lane = threadIdx.x & 63, wave = threadIdx.x >> 6;
  if (lane == 0) s[wave] = acc;
  __syncthreads();
  if (threadIdx.x == 0) out[0] = (s[0] + s[1] + s[2] + s[3]) * (1.0f / BATCH);
}

extern "C" void kernel_launch(void* const* d_in, const int* in_sizes, int n_in,
                              void* d_out, int out_size, void* d_ws, size_t ws_size,
                              hipStream_t stream) {
  const float* pos_b = (const float*)d_in[0];
  const float* neg_b = (const float*)d_in[1];
  const int* r_idx = (const int*)d_in[2];
  const float* rel_emb = (const float*)d_in[3];
  float* out = (float*)d_out;

  float* pA = (float*)d_ws + WS_PA;
  float* pB = (float*)d_ws + WS_PB;
  int* order = (int*)d_ws + WS_ORDER;

  sort_kernel<<<1, 1024, 0, stream>>>(r_idx, order);
  // A/B experiment, same total work: first half of groups WITH XCD swizzle,
  // second half WITHOUT. Durations separate in rocprof.
  score_kernel<1><<<HALF, 256, 0, stream>>>(pos_b, neg_b, r_idx, rel_emb,
                                            order, pA, pB, HALF, 0);
  score_kernel<0><<<HALF, 256, 0, stream>>>(pos_b, neg_b, r_idx, rel_emb,
                                            order, pA, pB, HALF, HALF);
  reduce_kernel<<<1, 256, 0, stream>>>(pA, pB, out);
}